// Round 1
// 704.123 us; speedup vs baseline: 1.0636x; 1.0636x over previous
//
#include <hip/hip_runtime.h>

#define KK 12
#define DIM 128
#define BNTOT 65536

typedef __attribute__((ext_vector_type(8))) short bf16x8;
typedef __attribute__((ext_vector_type(4))) float floatx4;

// round-to-nearest-even f32 -> bf16 (inputs are finite; no NaN handling needed)
static __device__ __forceinline__ unsigned short f2bf(float x) {
  unsigned u = __float_as_uint(x);
  unsigned r = (u + 0x7fffu + ((u >> 16) & 1u)) >> 16;
  return (unsigned short)r;
}
static __device__ __forceinline__ unsigned pk2(float a, float b) {
  return (unsigned)f2bf(a) | ((unsigned)f2bf(b) << 16);
}

// ---------------------------------------------------------------------------
// Kernel 1: per-(b,n) attention -> agg[bn][128]
// 512 threads = 8 waves/block, one wave per bn, 4 bn-iterations, 32 bn/block.
// Barrier-free after staging: scores exchanged via shfl butterfly.
// Software-pipelined: next bn's stage-2 loads issued during current compute
// (they cover the whole next 12x128 nbr tile -> also warm next afrag pack).
// ---------------------------------------------------------------------------
template <bool BF16AGG>
__global__ __launch_bounds__(512, 4) void k1_attn(
    const float* __restrict__ nbr,    // [BN, 12, 128]
    const float* __restrict__ nw,     // [BN, 12]
    const float* __restrict__ extra,  // [BN, 128]
    const float* __restrict__ w1,     // [129, 128]
    const float* __restrict__ w2,     // [128]
    void* __restrict__ aggout)        // [BN, 128] bf16 or f32
{
  __shared__ unsigned short w1t[128][136];  // bf16 bits, w1t[n][k], padded
  __shared__ float wpair[128][2];           // {w1[128][n], w2[n]}

  const int tid = threadIdx.x;
  for (int idx = tid; idx < 128 * 128; idx += 512) {
    int k = idx >> 7, n = idx & 127;        // w1[k][n], coalesced over n
    w1t[n][k] = f2bf(w1[idx]);
  }
  if (tid < 128) { wpair[tid][0] = w1[16384 + tid]; wpair[tid][1] = w2[tid]; }
  __syncthreads();  // the ONLY barrier; w1t/wpair read-only afterwards

  const int lane = tid & 63;
  const int wave = tid >> 6;
  const int m = lane & 15;       // A-row (neighbor index; 12..15 zero padding)
  const int quad = lane >> 4;
  const int half = lane >> 5;
  const int dq = (lane & 31) * 4;
  const int bn0 = blockIdx.x * 32 + wave * 4;

  // ---- prologue: stage-2 loads + warmers for it=0
  float4 s2buf[6];
  {
    const float* nb = nbr + (size_t)bn0 * (KK * DIM);
#pragma unroll
    for (int k = 0; k < 6; ++k)
      s2buf[k] = *(const float4*)(nb + (half * 6 + k) * DIM + dq);
  }
  {
    float4 exw = *(const float4*)(extra + (size_t)bn0 * DIM + dq);  // warm L1/L2
    asm volatile("" ::"v"(exw.x), "v"(exw.y), "v"(exw.z), "v"(exw.w));
  }
  float wrow[4];
#pragma unroll
  for (int r = 0; r < 4; ++r) {
    int row = quad * 4 + r;
    wrow[r] = (row < KK) ? nw[(size_t)bn0 * KK + row] : 0.f;
  }

  float4 s2n[6];
  float4 exn;
  float nwn[4];

#pragma unroll
  for (int it = 0; it < 4; ++it) {
    const int bn = bn0 + it;
    const float* nb_bn = nbr + (size_t)bn * (KK * DIM);
    const float* ex_bn = extra + (size_t)bn * DIM;

    // ---- A fragments: en[m][f] = extra[f]*neighbor[m][f]  (loads are L1/L2
    //      hot: the stage-2 prefetch issued last iteration covered this tile)
    bf16x8 afrag[4];
#pragma unroll
    for (int s = 0; s < 4; ++s) {
      const int f0 = s * 32 + quad * 8;
      float4 e0 = *(const float4*)(ex_bn + f0);
      float4 e1 = *(const float4*)(ex_bn + f0 + 4);
      float4 n0 = make_float4(0.f, 0.f, 0.f, 0.f), n1 = n0;
      if (m < KK) {
        n0 = *(const float4*)(nb_bn + m * DIM + f0);
        n1 = *(const float4*)(nb_bn + m * DIM + f0 + 4);
      }
      union { bf16x8 v; unsigned u[4]; } pk;
      pk.u[0] = pk2(e0.x * n0.x, e0.y * n0.y);
      pk.u[1] = pk2(e0.z * n0.z, e0.w * n0.w);
      pk.u[2] = pk2(e1.x * n1.x, e1.y * n1.y);
      pk.u[3] = pk2(e1.z * n1.z, e1.w * n1.w);
      afrag[s] = pk.v;
    }

    // ---- issue next iteration's loads (HBM latency hides under the tail)
    if (it < 3) {
      const float* nb2 = nb_bn + (KK * DIM);
#pragma unroll
      for (int k = 0; k < 6; ++k)
        s2n[k] = *(const float4*)(nb2 + (half * 6 + k) * DIM + dq);
      exn = *(const float4*)(ex_bn + DIM + dq);
#pragma unroll
      for (int r = 0; r < 4; ++r) {
        int row = quad * 4 + r;
        nwn[r] = (row < KK) ? nw[(size_t)(bn + 1) * KK + row] : 0.f;
      }
    }

    // ---- alpha = en @ w1[0:128,:], nt-outer (4-reg acc), fused epilogue:
    //      + rank-1 edge-weight term, leaky_relu(0.2), dot w2 -> part[r]
    // C layout (m89): col = lane&15 (+16*nt), row = quad*4 + r
    float part[4] = {0.f, 0.f, 0.f, 0.f};
#pragma unroll
    for (int nt = 0; nt < 8; ++nt) {
      floatx4 acc = (floatx4){0.f, 0.f, 0.f, 0.f};
#pragma unroll
      for (int s = 0; s < 4; ++s) {
        bf16x8 bfrag = *(const bf16x8*)&w1t[nt * 16 + m][s * 32 + quad * 8];
        acc = __builtin_amdgcn_mfma_f32_16x16x32_bf16(afrag[s], bfrag, acc, 0, 0, 0);
      }
      const int col = nt * 16 + m;
      const float wl = wpair[col][0], w2c = wpair[col][1];
#pragma unroll
      for (int r = 0; r < 4; ++r) {
        float v = acc[r] + wrow[r] * wl;
        v = (v > 0.f) ? v : 0.2f * v;
        part[r] += v * w2c;
      }
    }

    // ---- reduce over the 16 col-lanes; result replicated within each quad
#pragma unroll
    for (int r = 0; r < 4; ++r) {
      float p = part[r];
      p += __shfl_xor(p, 1); p += __shfl_xor(p, 2);
      p += __shfl_xor(p, 4); p += __shfl_xor(p, 8);
      part[r] = p;
    }

    // ---- softmax stats via butterfly (no LDS, no barrier)
    // local (max, expsum) over this quad's 4 rows; quad 3 rows are padding
    float ml = fmaxf(fmaxf(part[0], part[1]), fmaxf(part[2], part[3]));
    float sl = __expf(part[0] - ml) + __expf(part[1] - ml) +
               __expf(part[2] - ml) + __expf(part[3] - ml);
    if (quad == 3) { ml = -1e30f; sl = 0.f; }
    {
      float mo = __shfl_xor(ml, 16), so = __shfl_xor(sl, 16);
      float mn = fmaxf(ml, mo);
      sl = sl * __expf(ml - mn) + so * __expf(mo - mn); ml = mn;
      mo = __shfl_xor(ml, 32); so = __shfl_xor(sl, 32);
      mn = fmaxf(ml, mo);
      sl = sl * __expf(ml - mn) + so * __expf(mo - mn); ml = mn;
    }

    // ---- gather this half's 6 row-scores (rows half*6 .. half*6+5)
    float x0 = __shfl_xor(part[0], 16), x1 = __shfl_xor(part[1], 16);
    float x2 = __shfl_xor(part[2], 16), x3 = __shfl_xor(part[3], 16);
    const bool up1 = (quad & 1);
    float lo0 = up1 ? x0 : part[0];
    float lo1 = up1 ? x1 : part[1];
    float lo2 = up1 ? x2 : part[2];
    float lo3 = up1 ? x3 : part[3];
    float lo4 = up1 ? part[0] : x0;
    float lo5 = up1 ? part[1] : x1;
    float lo6 = up1 ? part[2] : x2;
    float lo7 = up1 ? part[3] : x3;
    float t6 = __shfl_xor(lo6, 32);   // rows 6,7 cross the half boundary
    float t7 = __shfl_xor(lo7, 32);
    float q0 = half ? t6 : lo0;
    float q1 = half ? t7 : lo1;
    float q2 = half ? lo0 : lo2;
    float q3 = half ? lo1 : lo3;
    float q4 = half ? lo2 : lo4;
    float q5 = half ? lo3 : lo5;
    float p0 = __expf(q0 - ml), p1 = __expf(q1 - ml), p2 = __expf(q2 - ml);
    float p3 = __expf(q3 - ml), p4 = __expf(q4 - ml), p5 = __expf(q5 - ml);
    const float inv = 1.f / sl;

    // ---- agg[d] = sum_k p[k]*neighbor[k][d] from the prefetched registers
    float4 a4;
    a4.x = p0 * s2buf[0].x + p1 * s2buf[1].x + p2 * s2buf[2].x +
           p3 * s2buf[3].x + p4 * s2buf[4].x + p5 * s2buf[5].x;
    a4.y = p0 * s2buf[0].y + p1 * s2buf[1].y + p2 * s2buf[2].y +
           p3 * s2buf[3].y + p4 * s2buf[4].y + p5 * s2buf[5].y;
    a4.z = p0 * s2buf[0].z + p1 * s2buf[1].z + p2 * s2buf[2].z +
           p3 * s2buf[3].z + p4 * s2buf[4].z + p5 * s2buf[5].z;
    a4.w = p0 * s2buf[0].w + p1 * s2buf[1].w + p2 * s2buf[2].w +
           p3 * s2buf[3].w + p4 * s2buf[4].w + p5 * s2buf[5].w;
    a4.x += __shfl_xor(a4.x, 32);
    a4.y += __shfl_xor(a4.y, 32);
    a4.z += __shfl_xor(a4.z, 32);
    a4.w += __shfl_xor(a4.w, 32);
    if (half == 0) {
      if constexpr (BF16AGG) {
        // identical bits to k2's former pk2 rounding of f32 agg
        uint2 o;
        o.x = pk2(a4.x * inv, a4.y * inv);
        o.y = pk2(a4.z * inv, a4.w * inv);
        *(uint2*)((unsigned short*)aggout + (size_t)bn * DIM + dq) = o;
      } else {
        float4 o = make_float4(a4.x * inv, a4.y * inv, a4.z * inv, a4.w * inv);
        *(float4*)((float*)aggout + (size_t)bn * DIM + dq) = o;
      }
    }

    // ---- rotate prefetch buffers
    if (it < 3) {
#pragma unroll
      for (int k = 0; k < 6; ++k) s2buf[k] = s2n[k];
#pragma unroll
      for (int r = 0; r < 4; ++r) wrow[r] = nwn[r];
      asm volatile("" ::"v"(exn.x), "v"(exn.y), "v"(exn.z), "v"(exn.w));  // keep warmer alive
    }
  }
}

// ---------------------------------------------------------------------------
// Kernel 2 (bf16-agg path): out = relu([self|agg] @ w3), column-split.
// Each block owns 64 output cols (half of w3 -> 32KB LDS) and 128 rows.
// 512 threads = 8 waves; 4 blocks/CU -> 32 waves/CU (was 8).
// ---------------------------------------------------------------------------
__global__ __launch_bounds__(512, 6) void k2_bf(
    const float* __restrict__ selfv,          // [BN, 128] f32
    const unsigned short* __restrict__ aggb,  // [BN, 128] bf16 bits
    const float* __restrict__ w3,             // [256, 128] f32
    float* __restrict__ out)                  // [BN, 128] f32
{
  __shared__ unsigned short w3h[64 * 256];  // logical [n(64)][k(256)], 16B-block XOR swizzle
  const int tid = threadIdx.x;
  const int ch = blockIdx.x >> 9;   // column half (0: cols 0..63, 1: 64..127)
  const int rb = blockIdx.x & 511;  // row block
  for (int idx = tid; idx < 64 * 256; idx += 512) {
    int k = idx >> 6, n = idx & 63;  // w3[k][ch*64+n], coalesced over n
    int pos = (((k >> 3) ^ (n & 31)) << 3) | (k & 7);
    w3h[n * 256 + pos] = f2bf(w3[k * 128 + ch * 64 + n]);
  }
  __syncthreads();

  const int lane = tid & 63;
  const int wave = tid >> 6;
  const int m = lane & 15, quad = lane >> 4;
  const int rowbase = rb * 128 + wave * 16;
  const float* xs = selfv + (size_t)(rowbase + m) * DIM;
  const unsigned short* xa = aggb + (size_t)(rowbase + m) * DIM;

  floatx4 acc[4];
#pragma unroll
  for (int nt = 0; nt < 4; ++nt) acc[nt] = (floatx4){0.f, 0.f, 0.f, 0.f};

  // self half (f32 -> pack)
#pragma unroll 2
  for (int s = 0; s < 4; ++s) {
    const int k0 = s * 32 + quad * 8;
    float4 v0 = *(const float4*)(xs + k0);
    float4 v1 = *(const float4*)(xs + k0 + 4);
    union { bf16x8 v; unsigned u[4]; } pk;
    pk.u[0] = pk2(v0.x, v0.y);
    pk.u[1] = pk2(v0.z, v0.w);
    pk.u[2] = pk2(v1.x, v1.y);
    pk.u[3] = pk2(v1.z, v1.w);
#pragma unroll
    for (int nt = 0; nt < 4; ++nt) {
      int n = nt * 16 + m;
      int bk = (((s * 4 + quad) ^ (n & 31)) << 3);
      bf16x8 bfrag = *(const bf16x8*)&w3h[n * 256 + bk];
      acc[nt] = __builtin_amdgcn_mfma_f32_16x16x32_bf16(pk.v, bfrag, acc[nt], 0, 0, 0);
    }
  }
  // agg half (already bf16 -> direct fragment load, no pack)
#pragma unroll
  for (int s = 4; s < 8; ++s) {
    const int k0 = (s - 4) * 32 + quad * 8;
    bf16x8 av = *(const bf16x8*)(xa + k0);
#pragma unroll
    for (int nt = 0; nt < 4; ++nt) {
      int n = nt * 16 + m;
      int bk = (((s * 4 + quad) ^ (n & 31)) << 3);
      bf16x8 bfrag = *(const bf16x8*)&w3h[n * 256 + bk];
      acc[nt] = __builtin_amdgcn_mfma_f32_16x16x32_bf16(av, bfrag, acc[nt], 0, 0, 0);
    }
  }
#pragma unroll
  for (int nt = 0; nt < 4; ++nt) {
    int col = ch * 64 + nt * 16 + m;
#pragma unroll
    for (int r = 0; r < 4; ++r) {
      int orow = rowbase + quad * 4 + r;
      out[(size_t)orow * DIM + col] = fmaxf(acc[nt][r], 0.f);
    }
  }
}

// ---------------------------------------------------------------------------
// Fallback kernel 2 (no workspace): identical to the prior verified version,
// reads f32 agg aliased into `out` with per-block read-before-write rows.
// ---------------------------------------------------------------------------
__global__ __launch_bounds__(256) void k2_old(
    const float* __restrict__ selfv,
    const float* __restrict__ agg,
    const float* __restrict__ w3,
    float* __restrict__ out)
{
  __shared__ unsigned short w3t[128 * 256];
  const int tid = threadIdx.x;
  for (int idx = tid; idx < 256 * 128; idx += 256) {
    int k = idx >> 7, n = idx & 127;
    int pos = (((k >> 3) ^ (n & 31)) << 3) | (k & 7);
    w3t[n * 256 + pos] = f2bf(w3[idx]);
  }
  __syncthreads();

  const int wave = tid >> 6, lane = tid & 63;
  const int m = lane & 15, quad = lane >> 4;

  for (int it = 0; it < 2; ++it) {
    const int rowbase = blockIdx.x * 128 + it * 64 + wave * 16;
    const float* xs = selfv + (size_t)(rowbase + m) * DIM;
    const float* xa = agg + (size_t)(rowbase + m) * DIM;
    floatx4 acc[8];
#pragma unroll
    for (int nt = 0; nt < 8; ++nt) acc[nt] = (floatx4){0.f, 0.f, 0.f, 0.f};
#pragma unroll
    for (int s = 0; s < 8; ++s) {
      const int k0 = s * 32 + quad * 8;
      const float* src = (s < 4) ? (xs + k0) : (xa + (k0 - 128));
      float4 v0 = *(const float4*)src;
      float4 v1 = *(const float4*)(src + 4);
      union { bf16x8 v; unsigned u[4]; } pk;
      pk.u[0] = pk2(v0.x, v0.y);
      pk.u[1] = pk2(v0.z, v0.w);
      pk.u[2] = pk2(v1.x, v1.y);
      pk.u[3] = pk2(v1.z, v1.w);
#pragma unroll
      for (int nt = 0; nt < 8; ++nt) {
        int n = nt * 16 + m;
        int bk = (((s * 4 + quad) ^ (n & 31)) << 3);
        bf16x8 bfrag = *(const bf16x8*)&w3t[n * 256 + bk];
        acc[nt] = __builtin_amdgcn_mfma_f32_16x16x32_bf16(pk.v, bfrag, acc[nt], 0, 0, 0);
      }
    }
#pragma unroll
    for (int nt = 0; nt < 8; ++nt) {
      int col = nt * 16 + m;
#pragma unroll
      for (int r = 0; r < 4; ++r) {
        int orow = rowbase + quad * 4 + r;
        out[(size_t)orow * DIM + col] = fmaxf(acc[nt][r], 0.f);
      }
    }
  }
}

extern "C" void kernel_launch(void* const* d_in, const int* in_sizes, int n_in,
                              void* d_out, int out_size, void* d_ws, size_t ws_size,
                              hipStream_t stream) {
  const float* selfv = (const float*)d_in[0];
  const float* nbr   = (const float*)d_in[1];
  const float* nw    = (const float*)d_in[2];
  const float* extra = (const float*)d_in[3];
  // d_in[4] = masks (all ones; unused by reference math), d_in[5] = batch_size
  const float* w1 = (const float*)d_in[6];
  const float* w2 = (const float*)d_in[7];
  const float* w3 = (const float*)d_in[8];
  float* out = (float*)d_out;

  const size_t need_bf = (size_t)BNTOT * DIM * sizeof(unsigned short);
  if (ws_size >= need_bf) {
    // fast path: bf16 agg staged in workspace
    k1_attn<true><<<BNTOT / 32, 512, 0, stream>>>(nbr, nw, extra, w1, w2, d_ws);
    k2_bf<<<1024, 512, 0, stream>>>(selfv, (const unsigned short*)d_ws, w3, out);
  } else {
    // fallback: f32 agg aliased into out (row-disjoint blocks, hazard-free)
    k1_attn<false><<<BNTOT / 32, 512, 0, stream>>>(nbr, nw, extra, w1, w2, out);
    k2_old<<<BNTOT / 128, 256, 0, stream>>>(selfv, (const float*)out, w3, out);
  }
}

// Round 2
// 653.202 us; speedup vs baseline: 1.1466x; 1.0780x over previous
//
#include <hip/hip_runtime.h>

#define KK 12
#define DIM 128
#define BNTOT 65536

typedef __attribute__((ext_vector_type(8))) short bf16x8;
typedef __attribute__((ext_vector_type(4))) float floatx4;

// round-to-nearest-even f32 -> bf16 (inputs are finite; no NaN handling needed)
static __device__ __forceinline__ unsigned short f2bf(float x) {
  unsigned u = __float_as_uint(x);
  unsigned r = (u + 0x7fffu + ((u >> 16) & 1u)) >> 16;
  return (unsigned short)r;
}
static __device__ __forceinline__ unsigned pk2(float a, float b) {
  return (unsigned)f2bf(a) | ((unsigned)f2bf(b) << 16);
}

// ---------------------------------------------------------------------------
// Kernel 1: per-(b,n) attention -> agg[bn][128]
// 512 threads = 8 waves/block, one wave per bn, 4 bn-iterations, 32 bn/block.
// Barrier-free after staging: scores exchanged via shfl butterfly.
// Software-pipelined: next bn's stage-2 loads issued during current compute.
// __launch_bounds__(512, 2): 2 blocks/CU target -> 128-VGPR cap. (512,4)
// empirically forced a 64-VGPR cap and ~500 MB of scratch spill traffic.
// ---------------------------------------------------------------------------
template <bool BF16AGG>
__global__ __launch_bounds__(512, 2) void k1_attn(
    const float* __restrict__ nbr,    // [BN, 12, 128]
    const float* __restrict__ nw,     // [BN, 12]
    const float* __restrict__ extra,  // [BN, 128]
    const float* __restrict__ w1,     // [129, 128]
    const float* __restrict__ w2,     // [128]
    void* __restrict__ aggout)        // [BN, 128] bf16 or f32
{
  __shared__ unsigned short w1t[128][136];  // bf16 bits, w1t[n][k], padded
  __shared__ float wpair[128][2];           // {w1[128][n], w2[n]}

  const int tid = threadIdx.x;
  for (int idx = tid; idx < 128 * 128; idx += 512) {
    int k = idx >> 7, n = idx & 127;        // w1[k][n], coalesced over n
    w1t[n][k] = f2bf(w1[idx]);
  }
  if (tid < 128) { wpair[tid][0] = w1[16384 + tid]; wpair[tid][1] = w2[tid]; }
  __syncthreads();  // the ONLY barrier; w1t/wpair read-only afterwards

  const int lane = tid & 63;
  const int wave = tid >> 6;
  const int m = lane & 15;       // A-row (neighbor index; 12..15 zero padding)
  const int quad = lane >> 4;
  const int half = lane >> 5;
  const int dq = (lane & 31) * 4;
  const int bn0 = blockIdx.x * 32 + wave * 4;

  // ---- prologue: stage-2 loads + warmers for it=0
  float4 s2buf[6];
  {
    const float* nb = nbr + (size_t)bn0 * (KK * DIM);
#pragma unroll
    for (int k = 0; k < 6; ++k)
      s2buf[k] = *(const float4*)(nb + (half * 6 + k) * DIM + dq);
  }
  {
    float4 exw = *(const float4*)(extra + (size_t)bn0 * DIM + dq);  // warm L1/L2
    asm volatile("" ::"v"(exw.x), "v"(exw.y), "v"(exw.z), "v"(exw.w));
  }
  float wrow[4];
#pragma unroll
  for (int r = 0; r < 4; ++r) {
    int row = quad * 4 + r;
    wrow[r] = (row < KK) ? nw[(size_t)bn0 * KK + row] : 0.f;
  }

  float4 s2n[6];
  float4 exn;
  float nwn[4];

#pragma unroll
  for (int it = 0; it < 4; ++it) {
    const int bn = bn0 + it;
    const float* nb_bn = nbr + (size_t)bn * (KK * DIM);
    const float* ex_bn = extra + (size_t)bn * DIM;

    // ---- A fragments: en[m][f] = extra[f]*neighbor[m][f]  (loads are L1/L2
    //      hot: the stage-2 prefetch issued last iteration covered this tile)
    bf16x8 afrag[4];
#pragma unroll
    for (int s = 0; s < 4; ++s) {
      const int f0 = s * 32 + quad * 8;
      float4 e0 = *(const float4*)(ex_bn + f0);
      float4 e1 = *(const float4*)(ex_bn + f0 + 4);
      float4 n0 = make_float4(0.f, 0.f, 0.f, 0.f), n1 = n0;
      if (m < KK) {
        n0 = *(const float4*)(nb_bn + m * DIM + f0);
        n1 = *(const float4*)(nb_bn + m * DIM + f0 + 4);
      }
      union { bf16x8 v; unsigned u[4]; } pk;
      pk.u[0] = pk2(e0.x * n0.x, e0.y * n0.y);
      pk.u[1] = pk2(e0.z * n0.z, e0.w * n0.w);
      pk.u[2] = pk2(e1.x * n1.x, e1.y * n1.y);
      pk.u[3] = pk2(e1.z * n1.z, e1.w * n1.w);
      afrag[s] = pk.v;
    }

    // ---- issue next iteration's loads (HBM latency hides under the tail)
    if (it < 3) {
      const float* nb2 = nb_bn + (KK * DIM);
#pragma unroll
      for (int k = 0; k < 6; ++k)
        s2n[k] = *(const float4*)(nb2 + (half * 6 + k) * DIM + dq);
      exn = *(const float4*)(ex_bn + DIM + dq);
#pragma unroll
      for (int r = 0; r < 4; ++r) {
        int row = quad * 4 + r;
        nwn[r] = (row < KK) ? nw[(size_t)(bn + 1) * KK + row] : 0.f;
      }
    }

    // ---- alpha = en @ w1[0:128,:], nt-outer (4-reg acc), fused epilogue:
    //      + rank-1 edge-weight term, leaky_relu(0.2), dot w2 -> part[r]
    // C layout (m89): col = lane&15 (+16*nt), row = quad*4 + r
    float part[4] = {0.f, 0.f, 0.f, 0.f};
#pragma unroll
    for (int nt = 0; nt < 8; ++nt) {
      floatx4 acc = (floatx4){0.f, 0.f, 0.f, 0.f};
#pragma unroll
      for (int s = 0; s < 4; ++s) {
        bf16x8 bfrag = *(const bf16x8*)&w1t[nt * 16 + m][s * 32 + quad * 8];
        acc = __builtin_amdgcn_mfma_f32_16x16x32_bf16(afrag[s], bfrag, acc, 0, 0, 0);
      }
      const int col = nt * 16 + m;
      const float wl = wpair[col][0], w2c = wpair[col][1];
#pragma unroll
      for (int r = 0; r < 4; ++r) {
        float v = acc[r] + wrow[r] * wl;
        v = (v > 0.f) ? v : 0.2f * v;
        part[r] += v * w2c;
      }
    }

    // ---- reduce over the 16 col-lanes; result replicated within each quad
#pragma unroll
    for (int r = 0; r < 4; ++r) {
      float p = part[r];
      p += __shfl_xor(p, 1); p += __shfl_xor(p, 2);
      p += __shfl_xor(p, 4); p += __shfl_xor(p, 8);
      part[r] = p;
    }

    // ---- softmax stats via butterfly (no LDS, no barrier)
    float ml = fmaxf(fmaxf(part[0], part[1]), fmaxf(part[2], part[3]));
    float sl = __expf(part[0] - ml) + __expf(part[1] - ml) +
               __expf(part[2] - ml) + __expf(part[3] - ml);
    if (quad == 3) { ml = -1e30f; sl = 0.f; }
    {
      float mo = __shfl_xor(ml, 16), so = __shfl_xor(sl, 16);
      float mn = fmaxf(ml, mo);
      sl = sl * __expf(ml - mn) + so * __expf(mo - mn); ml = mn;
      mo = __shfl_xor(ml, 32); so = __shfl_xor(sl, 32);
      mn = fmaxf(ml, mo);
      sl = sl * __expf(ml - mn) + so * __expf(mo - mn); ml = mn;
    }

    // ---- gather this half's 6 row-scores (rows half*6 .. half*6+5)
    float x0 = __shfl_xor(part[0], 16), x1 = __shfl_xor(part[1], 16);
    float x2 = __shfl_xor(part[2], 16), x3 = __shfl_xor(part[3], 16);
    const bool up1 = (quad & 1);
    float lo0 = up1 ? x0 : part[0];
    float lo1 = up1 ? x1 : part[1];
    float lo2 = up1 ? x2 : part[2];
    float lo3 = up1 ? x3 : part[3];
    float lo4 = up1 ? part[0] : x0;
    float lo5 = up1 ? part[1] : x1;
    float lo6 = up1 ? part[2] : x2;
    float lo7 = up1 ? part[3] : x3;
    float t6 = __shfl_xor(lo6, 32);   // rows 6,7 cross the half boundary
    float t7 = __shfl_xor(lo7, 32);
    float q0 = half ? t6 : lo0;
    float q1 = half ? t7 : lo1;
    float q2 = half ? lo0 : lo2;
    float q3 = half ? lo1 : lo3;
    float q4 = half ? lo2 : lo4;
    float q5 = half ? lo3 : lo5;
    float p0 = __expf(q0 - ml), p1 = __expf(q1 - ml), p2 = __expf(q2 - ml);
    float p3 = __expf(q3 - ml), p4 = __expf(q4 - ml), p5 = __expf(q5 - ml);
    const float inv = 1.f / sl;

    // ---- agg[d] = sum_k p[k]*neighbor[k][d] from the prefetched registers
    float4 a4;
    a4.x = p0 * s2buf[0].x + p1 * s2buf[1].x + p2 * s2buf[2].x +
           p3 * s2buf[3].x + p4 * s2buf[4].x + p5 * s2buf[5].x;
    a4.y = p0 * s2buf[0].y + p1 * s2buf[1].y + p2 * s2buf[2].y +
           p3 * s2buf[3].y + p4 * s2buf[4].y + p5 * s2buf[5].y;
    a4.z = p0 * s2buf[0].z + p1 * s2buf[1].z + p2 * s2buf[2].z +
           p3 * s2buf[3].z + p4 * s2buf[4].z + p5 * s2buf[5].z;
    a4.w = p0 * s2buf[0].w + p1 * s2buf[1].w + p2 * s2buf[2].w +
           p3 * s2buf[3].w + p4 * s2buf[4].w + p5 * s2buf[5].w;
    a4.x += __shfl_xor(a4.x, 32);
    a4.y += __shfl_xor(a4.y, 32);
    a4.z += __shfl_xor(a4.z, 32);
    a4.w += __shfl_xor(a4.w, 32);
    if (half == 0) {
      if constexpr (BF16AGG) {
        // identical bits to k2's former pk2 rounding of f32 agg
        uint2 o;
        o.x = pk2(a4.x * inv, a4.y * inv);
        o.y = pk2(a4.z * inv, a4.w * inv);
        *(uint2*)((unsigned short*)aggout + (size_t)bn * DIM + dq) = o;
      } else {
        float4 o = make_float4(a4.x * inv, a4.y * inv, a4.z * inv, a4.w * inv);
        *(float4*)((float*)aggout + (size_t)bn * DIM + dq) = o;
      }
    }

    // ---- rotate prefetch buffers
    if (it < 3) {
#pragma unroll
      for (int k = 0; k < 6; ++k) s2buf[k] = s2n[k];
#pragma unroll
      for (int r = 0; r < 4; ++r) wrow[r] = nwn[r];
      asm volatile("" ::"v"(exn.x), "v"(exn.y), "v"(exn.z), "v"(exn.w));  // keep warmer alive
    }
  }
}

// ---------------------------------------------------------------------------
// Kernel 2 (bf16-agg path): out = relu([self|agg] @ w3), column-split.
// Each block owns 64 output cols (half of w3 -> 32KB LDS) and 128 rows.
// 512 threads = 8 waves; (512,4): 4 blocks/CU -> 32 waves/CU, 64-VGPR cap
// (demand ~50, fits without spill).
// ---------------------------------------------------------------------------
__global__ __launch_bounds__(512, 4) void k2_bf(
    const float* __restrict__ selfv,          // [BN, 128] f32
    const unsigned short* __restrict__ aggb,  // [BN, 128] bf16 bits
    const float* __restrict__ w3,             // [256, 128] f32
    float* __restrict__ out)                  // [BN, 128] f32
{
  __shared__ unsigned short w3h[64 * 256];  // logical [n(64)][k(256)], 16B-block XOR swizzle
  const int tid = threadIdx.x;
  const int ch = blockIdx.x >> 9;   // column half (0: cols 0..63, 1: 64..127)
  const int rb = blockIdx.x & 511;  // row block
  for (int idx = tid; idx < 64 * 256; idx += 512) {
    int k = idx >> 6, n = idx & 63;  // w3[k][ch*64+n], coalesced over n
    int pos = (((k >> 3) ^ (n & 31)) << 3) | (k & 7);
    w3h[n * 256 + pos] = f2bf(w3[k * 128 + ch * 64 + n]);
  }
  __syncthreads();

  const int lane = tid & 63;
  const int wave = tid >> 6;
  const int m = lane & 15, quad = lane >> 4;
  const int rowbase = rb * 128 + wave * 16;
  const float* xs = selfv + (size_t)(rowbase + m) * DIM;
  const unsigned short* xa = aggb + (size_t)(rowbase + m) * DIM;

  floatx4 acc[4];
#pragma unroll
  for (int nt = 0; nt < 4; ++nt) acc[nt] = (floatx4){0.f, 0.f, 0.f, 0.f};

  // self half (f32 -> pack)
#pragma unroll 2
  for (int s = 0; s < 4; ++s) {
    const int k0 = s * 32 + quad * 8;
    float4 v0 = *(const float4*)(xs + k0);
    float4 v1 = *(const float4*)(xs + k0 + 4);
    union { bf16x8 v; unsigned u[4]; } pk;
    pk.u[0] = pk2(v0.x, v0.y);
    pk.u[1] = pk2(v0.z, v0.w);
    pk.u[2] = pk2(v1.x, v1.y);
    pk.u[3] = pk2(v1.z, v1.w);
#pragma unroll
    for (int nt = 0; nt < 4; ++nt) {
      int n = nt * 16 + m;
      int bk = (((s * 4 + quad) ^ (n & 31)) << 3);
      bf16x8 bfrag = *(const bf16x8*)&w3h[n * 256 + bk];
      acc[nt] = __builtin_amdgcn_mfma_f32_16x16x32_bf16(pk.v, bfrag, acc[nt], 0, 0, 0);
    }
  }
  // agg half (already bf16 -> direct fragment load, no pack)
#pragma unroll
  for (int s = 4; s < 8; ++s) {
    const int k0 = (s - 4) * 32 + quad * 8;
    bf16x8 av = *(const bf16x8*)(xa + k0);
#pragma unroll
    for (int nt = 0; nt < 4; ++nt) {
      int n = nt * 16 + m;
      int bk = (((s * 4 + quad) ^ (n & 31)) << 3);
      bf16x8 bfrag = *(const bf16x8*)&w3h[n * 256 + bk];
      acc[nt] = __builtin_amdgcn_mfma_f32_16x16x32_bf16(av, bfrag, acc[nt], 0, 0, 0);
    }
  }
#pragma unroll
  for (int nt = 0; nt < 4; ++nt) {
    int col = ch * 64 + nt * 16 + m;
#pragma unroll
    for (int r = 0; r < 4; ++r) {
      int orow = rowbase + quad * 4 + r;
      out[(size_t)orow * DIM + col] = fmaxf(acc[nt][r], 0.f);
    }
  }
}

// ---------------------------------------------------------------------------
// Fallback kernel 2 (no workspace): identical to the prior verified version,
// reads f32 agg aliased into `out` with per-block read-before-write rows.
// ---------------------------------------------------------------------------
__global__ __launch_bounds__(256) void k2_old(
    const float* __restrict__ selfv,
    const float* __restrict__ agg,
    const float* __restrict__ w3,
    float* __restrict__ out)
{
  __shared__ unsigned short w3t[128 * 256];
  const int tid = threadIdx.x;
  for (int idx = tid; idx < 256 * 128; idx += 256) {
    int k = idx >> 7, n = idx & 127;
    int pos = (((k >> 3) ^ (n & 31)) << 3) | (k & 7);
    w3t[n * 256 + pos] = f2bf(w3[idx]);
  }
  __syncthreads();

  const int wave = tid >> 6, lane = tid & 63;
  const int m = lane & 15, quad = lane >> 4;

  for (int it = 0; it < 2; ++it) {
    const int rowbase = blockIdx.x * 128 + it * 64 + wave * 16;
    const float* xs = selfv + (size_t)(rowbase + m) * DIM;
    const float* xa = agg + (size_t)(rowbase + m) * DIM;
    floatx4 acc[8];
#pragma unroll
    for (int nt = 0; nt < 8; ++nt) acc[nt] = (floatx4){0.f, 0.f, 0.f, 0.f};
#pragma unroll
    for (int s = 0; s < 8; ++s) {
      const int k0 = s * 32 + quad * 8;
      const float* src = (s < 4) ? (xs + k0) : (xa + (k0 - 128));
      float4 v0 = *(const float4*)src;
      float4 v1 = *(const float4*)(src + 4);
      union { bf16x8 v; unsigned u[4]; } pk;
      pk.u[0] = pk2(v0.x, v0.y);
      pk.u[1] = pk2(v0.z, v0.w);
      pk.u[2] = pk2(v1.x, v1.y);
      pk.u[3] = pk2(v1.z, v1.w);
#pragma unroll
      for (int nt = 0; nt < 8; ++nt) {
        int n = nt * 16 + m;
        int bk = (((s * 4 + quad) ^ (n & 31)) << 3);
        bf16x8 bfrag = *(const bf16x8*)&w3t[n * 256 + bk];
        acc[nt] = __builtin_amdgcn_mfma_f32_16x16x32_bf16(pk.v, bfrag, acc[nt], 0, 0, 0);
      }
    }
#pragma unroll
    for (int nt = 0; nt < 8; ++nt) {
      int col = nt * 16 + m;
#pragma unroll
      for (int r = 0; r < 4; ++r) {
        int orow = rowbase + quad * 4 + r;
        out[(size_t)orow * DIM + col] = fmaxf(acc[nt][r], 0.f);
      }
    }
  }
}

extern "C" void kernel_launch(void* const* d_in, const int* in_sizes, int n_in,
                              void* d_out, int out_size, void* d_ws, size_t ws_size,
                              hipStream_t stream) {
  const float* selfv = (const float*)d_in[0];
  const float* nbr   = (const float*)d_in[1];
  const float* nw    = (const float*)d_in[2];
  const float* extra = (const float*)d_in[3];
  // d_in[4] = masks (all ones; unused by reference math), d_in[5] = batch_size
  const float* w1 = (const float*)d_in[6];
  const float* w2 = (const float*)d_in[7];
  const float* w3 = (const float*)d_in[8];
  float* out = (float*)d_out;

  const size_t need_bf = (size_t)BNTOT * DIM * sizeof(unsigned short);
  if (ws_size >= need_bf) {
    // fast path: bf16 agg staged in workspace
    k1_attn<true><<<BNTOT / 32, 512, 0, stream>>>(nbr, nw, extra, w1, w2, d_ws);
    k2_bf<<<1024, 512, 0, stream>>>(selfv, (const unsigned short*)d_ws, w3, out);
  } else {
    // fallback: f32 agg aliased into out (row-disjoint blocks, hazard-free)
    k1_attn<false><<<BNTOT / 32, 512, 0, stream>>>(nbr, nw, extra, w1, w2, out);
    k2_old<<<BNTOT / 128, 256, 0, stream>>>(selfv, (const float*)out, w3, out);
  }
}